// Round 1
// baseline (34.969 us; speedup 1.0000x reference)
//
#include <hip/hip_runtime.h>

#define B 32
#define S 512
#define D 384
#define T 3072
#define FPB 32            // frames per block in gather kernel
#define D4 (D/4)          // 96 float4 per frame

// d_out offsets (floats), concatenated in reference return order
#define OFF_OUT  0
#define OFF_DUR  (B*T*D)
#define OFF_MLEN (OFF_DUR + B*S)
#define OFF_MASK (OFF_MLEN + B)

// ---------------- Phase 1: durations, cumsum, mel_len ----------------
__global__ __launch_bounds__(512) void durations_kernel(
    const float* __restrict__ logd, const int* __restrict__ max_len_p,
    float* __restrict__ out, int* __restrict__ cum_ws, int* __restrict__ mlen_ws)
{
    const int b = blockIdx.x;
    const int s = threadIdx.x;

    float ld = logd[b * S + s];
    float dr = rintf(expf(ld) - 1.0f);   // rintf = round-half-even, matches jnp.round
    dr = fmaxf(dr, 0.0f);
    int d = (int)dr;

    out[OFF_DUR + b * S + s] = dr;

    // inclusive scan across 512 threads: wave-level shfl scan + wave offsets
    const int lane = s & 63;
    const int wave = s >> 6;
    int v = d;
    #pragma unroll
    for (int off = 1; off < 64; off <<= 1) {
        int u = __shfl_up(v, off, 64);
        if (lane >= off) v += u;
    }
    __shared__ int wsum[8];
    if (lane == 63) wsum[wave] = v;
    __syncthreads();
    if (s == 0) {
        int acc = 0;
        #pragma unroll
        for (int w = 0; w < 8; ++w) { int t = wsum[w]; wsum[w] = acc; acc += t; }
    }
    __syncthreads();
    const int cum = v + wsum[wave];
    cum_ws[b * S + s] = cum;

    if (s == S - 1) {
        int ml = min(cum, max_len_p[0]);
        mlen_ws[b] = ml;
        out[OFF_MLEN + b] = (float)ml;   // harness reads whole d_out as f32
    }
}

// ---------------- Phase 2: searchsorted + gather-copy ----------------
__global__ __launch_bounds__(256) void gather_kernel(
    const float* __restrict__ x, const int* __restrict__ cum_ws,
    const int* __restrict__ mlen_ws, float* __restrict__ outp)
{
    __shared__ int cum_s[S];
    __shared__ int sidx[FPB];
    __shared__ int mlen_s;

    const int b   = blockIdx.y;
    const int t0  = blockIdx.x * FPB;
    const int tid = threadIdx.x;

    for (int i = tid; i < S; i += 256) cum_s[i] = cum_ws[b * S + i];
    if (tid == 0) mlen_s = mlen_ws[b];
    __syncthreads();
    const int mlen = mlen_s;

    if (tid < FPB) {
        const int t = t0 + tid;
        int lo = 0;
        if (t < mlen) {                       // valid frames always find idx < S
            int hi = S;
            while (lo < hi) {
                int mid = (lo + hi) >> 1;
                if (cum_s[mid] <= t) lo = mid + 1; else hi = mid;
            }
            if (lo > S - 1) lo = S - 1;
        }
        sidx[tid] = lo;
        outp[OFF_MASK + (size_t)b * T + t] = (t < mlen) ? 0.0f : 1.0f;  // mask: True at padding
    }
    __syncthreads();

    const float4* x4 = (const float4*)(x + (size_t)b * S * D);
    float4* o4 = (float4*)(outp + OFF_OUT + (size_t)b * T * D + (size_t)t0 * D);

    #pragma unroll
    for (int i = 0; i < (FPB * D4) / 256; ++i) {
        int w = tid + i * 256;
        int f = w / D4;
        int e = w - f * D4;
        int t = t0 + f;
        float4 val;
        if (t < mlen) {
            val = x4[(size_t)sidx[f] * D4 + e];
        } else {
            val = make_float4(0.f, 0.f, 0.f, 0.f);
        }
        o4[(size_t)f * D4 + e] = val;
    }
}

extern "C" void kernel_launch(void* const* d_in, const int* in_sizes, int n_in,
                              void* d_out, int out_size, void* d_ws, size_t ws_size,
                              hipStream_t stream) {
    const float* x      = (const float*)d_in[0];
    const float* logd   = (const float*)d_in[1];
    const int*   maxlen = (const int*)d_in[2];
    float* out = (float*)d_out;

    int* cum_ws  = (int*)d_ws;
    int* mlen_ws = cum_ws + B * S;

    durations_kernel<<<B, 512, 0, stream>>>(logd, maxlen, out, cum_ws, mlen_ws);
    gather_kernel<<<dim3(T / FPB, B), 256, 0, stream>>>(x, cum_ws, mlen_ws, out);
}